// Round 1
// baseline (645.871 us; speedup 1.0000x reference)
//
#include <hip/hip_runtime.h>
#include <stdint.h>

#define T_TOK 8192
#define K_IN  4096
#define O_OUT 6144

typedef __attribute__((ext_vector_type(4))) float f32x4;
typedef __attribute__((ext_vector_type(8))) int i32x8;
typedef unsigned int uint32;

// ---------- helpers ----------

__device__ inline void load_lds_16(const void* g, void* l) {
    __builtin_amdgcn_global_load_lds(
        (const __attribute__((address_space(1))) unsigned int*)g,
        (__attribute__((address_space(3))) unsigned int*)l, 16, 0, 0);
}

// pack 4 floats -> 4 fp8 e4m3 bytes (RNE, saturating), byte i = input i
__device__ inline int pack4_fp8(float a, float b, float c, float d) {
    int r = __builtin_amdgcn_cvt_pk_fp8_f32(a, b, 0, false);  // bytes 0,1
    r = __builtin_amdgcn_cvt_pk_fp8_f32(c, d, r, true);       // bytes 2,3
    return r;
}

// ---------- kernel 1: per-token dynamic fp8 quantization of x ----------
__global__ __launch_bounds__(256) void quant_x(const float* __restrict__ x,
                                               uint32* __restrict__ xq,
                                               float* __restrict__ xscale) {
    const int t   = blockIdx.x;
    const int tid = threadIdx.x;
    const float4* row4 = (const float4*)(x + (size_t)t * K_IN);

    float4 v[4];
    float amax = 0.f;
#pragma unroll
    for (int j = 0; j < 4; ++j) {
        v[j] = row4[tid + j * 256];
        amax = fmaxf(amax, fmaxf(fmaxf(fabsf(v[j].x), fabsf(v[j].y)),
                                 fmaxf(fabsf(v[j].z), fabsf(v[j].w))));
    }
#pragma unroll
    for (int off = 32; off > 0; off >>= 1)
        amax = fmaxf(amax, __shfl_down(amax, off, 64));
    __shared__ float red[4];
    if ((tid & 63) == 0) red[tid >> 6] = amax;
    __syncthreads();
    amax = fmaxf(fmaxf(red[0], red[1]), fmaxf(red[2], red[3]));

    const float scale = fmaxf(amax, 1e-12f) / 448.0f;
    if (tid == 0) xscale[t] = scale;

    uint32* orow = xq + (size_t)t * (K_IN / 4);
#pragma unroll
    for (int j = 0; j < 4; ++j) {
        // correctly-rounded fp32 division matches the reference's x / x_scale
        float q0 = v[j].x / scale, q1 = v[j].y / scale;
        float q2 = v[j].z / scale, q3 = v[j].w / scale;
        orow[tid + j * 256] = (uint32)pack4_fp8(q0, q1, q2, q3);  // coalesced dword
    }
}

// ---------- kernel 2: fp8 quantization of W (scale applied inside GEMM) ----------
__global__ __launch_bounds__(256) void quant_w(const float* __restrict__ w,
                                               uint32* __restrict__ wq) {
    const size_t u = (size_t)blockIdx.x * 256 + threadIdx.x;  // dword index
    float4 v = ((const float4*)w)[u];
    wq[u] = (uint32)pack4_fp8(v.x, v.y, v.z, v.w);
}

// ---------- kernel 3: fp8 MX GEMM, 256x256x128 tile, 8 waves, 4-phase schedule ----
// A: [T][K] fp8 bytes, B: [O][K] fp8 bytes.
// C[t][o] = xs[t] * sum_kb s[o/128][kb] * (A.B)_kb   (Horner per K-tile)
// 8 waves as 2(M) x 4(N); per-wave 128x64 output (8x4 frags of 16x16) ->
// 85 FLOP per LDS byte (vs 64 at 64x64), balancing LDS pipe vs MX matrix pipe.
// Schedule: T3+T4+T5 — per K-tile 4 phases {ds_read quadrant | issue staging ->
// raw s_barrier -> lgkmcnt(0) -> setprio(1) 8xMFMA setprio(0) -> raw s_barrier},
// prefetch rounds for kb+1 issued in phases 0-1, single vmcnt(0) drain per
// K-tile via __syncthreads() at iteration end (loads had ~3 phases to land).
__global__ __launch_bounds__(512, 2) void gemm_fp8(const unsigned char* __restrict__ A,
                                                   const unsigned char* __restrict__ B,
                                                   const float* __restrict__ sinv,
                                                   const float* __restrict__ xscale,
                                                   float* __restrict__ C) {
    constexpr int BM = 256, BN = 256, BK = 128;
    constexpr int NKB = K_IN / BK;  // 32 K-tiles, one weight-scale block each
    // 128 KB dynamic LDS: buf p at p*65536, A tile 32 KB then B tile 32 KB.
    extern __shared__ unsigned char smem[];

    const int bn  = blockIdx.x;      // 24 o-tiles (each spans 2 scale blocks)
    const int bm  = blockIdx.y;      // 32 token tiles
    const int tid = threadIdx.x;
    const int lane = tid & 63;
    const int wv   = tid >> 6;
    const int wm   = (wv >> 2) * 128;   // wave M offset in tile
    const int wn   = (wv & 3) * 64;     // wave N offset in tile
    const int G2   = (lane >> 4) * 2;   // k-chunk pair for this lane group

    // ---- staging constants: linear LDS dest (gload_lds lane rule),
    //      swizzle applied on the GLOBAL source chunk index (rule #21)
    const int tr = tid >> 3;                  // row within a 64-row round group
    const int kc = (tid & 7) ^ (tr & 7);      // swizzled source 16B-chunk
    const unsigned char* Ag = A + (size_t)(bm * BM + tr) * K_IN + kc * 16;
    const unsigned char* Bg = B + (size_t)(bn * BN + tr) * K_IN + kc * 16;
    const int ldst = tid * 16;

    // ---- fragment-read constants: LDS slot j of row r holds global chunk j^(r&7);
    //      r&7 == lane&7 for all our fragment rows (wm, i*16 are mult. of 8)
    const int rA  = lane & 15;
    const int sw  = lane & 7;
    const int cs0 = ((G2    ) ^ sw) * 16;
    const int cs1 = ((G2 | 1) ^ sw) * 16;

    const float* srow = sinv + (size_t)(bn * 2 + (wn >> 7)) * NKB;

    f32x4 acc[8][4] = {};
    float s_prev = srow[0];

#define STAGE_A(p_, k0_) {                                                   \
    unsigned char* d_ = smem + (p_) * 65536 + ldst;                          \
    _Pragma("unroll")                                                        \
    for (int s_ = 0; s_ < 4; ++s_)                                           \
        load_lds_16(Ag + (size_t)(s_ * 64) * K_IN + (k0_), d_ + s_ * 8192); }
#define STAGE_B(p_, k0_) {                                                   \
    unsigned char* d_ = smem + (p_) * 65536 + 32768 + ldst;                  \
    _Pragma("unroll")                                                        \
    for (int s_ = 0; s_ < 4; ++s_)                                           \
        load_lds_16(Bg + (size_t)(s_ * 64) * K_IN + (k0_), d_ + s_ * 8192); }

    union F { i32x8 v; int4 h[2]; };
    F a[4], b01[2], b23[2];

#define LDA(d_, i_) { const unsigned char* q_ = pA + (wm + (i_) * 16 + rA) * 128; \
    (d_).h[0] = *(const int4*)(q_ + cs0); (d_).h[1] = *(const int4*)(q_ + cs1); }
#define LDB(d_, j_) { const unsigned char* q_ = pB + (wn + (j_) * 16 + rA) * 128; \
    (d_).h[0] = *(const int4*)(q_ + cs0); (d_).h[1] = *(const int4*)(q_ + cs1); }
#define MFMA(i_, j_, af_, bf_)                                              \
    acc[i_][j_] = __builtin_amdgcn_mfma_scale_f32_16x16x128_f8f6f4(         \
        (af_).v, (bf_).v, acc[i_][j_], 0 /*A=fp8*/, 0 /*B=fp8*/,            \
        0, 0x7f7f7f7f, 0, 0x7f7f7f7f);
// raw barrier (no implicit vmcnt drain — keeps prefetch in flight) with
// compiler memory fences so LDS ops can't migrate across (rule #18 family)
#define WAIT_MFMA_PHASE() do {                                              \
    asm volatile("" ::: "memory");                                          \
    __builtin_amdgcn_s_barrier();                                           \
    asm volatile("s_waitcnt lgkmcnt(0)" ::: "memory");                      \
    __builtin_amdgcn_sched_barrier(0);                                      \
    __builtin_amdgcn_s_setprio(1); } while (0)
#define END_MFMA_PHASE() do {                                               \
    __builtin_amdgcn_s_setprio(0);                                          \
    asm volatile("" ::: "memory");                                          \
    __builtin_amdgcn_s_barrier();                                           \
    asm volatile("" ::: "memory"); } while (0)

    // prologue: tile 0 into buf 0
    STAGE_A(0, 0); STAGE_B(0, 0);
    __syncthreads();

    for (int kb = 0; kb < NKB; ++kb) {
        const unsigned char* pA = smem + (kb & 1) * 65536;
        const unsigned char* pB = pA + 32768;
        const int  pn  = (kb & 1) ^ 1;
        const int  nk0 = (kb + 1) * BK;
        const bool pf  = (kb + 1) < NKB;
        // Horner: keep acc in units of 1/s_cur; rescale per quadrant below
        const float s_cur = srow[kb];
        const float rr = s_prev / s_cur;   // exactly 1.0 at kb==0
        s_prev = s_cur;

        // ---------- phase 0: quadrant i=0..3 x j=0..1 (+ prefetch A of kb+1)
        if (pf) STAGE_A(pn, nk0);
        LDA(a[0], 0) LDA(a[1], 1) LDA(a[2], 2) LDA(a[3], 3)
        LDB(b01[0], 0) LDB(b01[1], 1)
#pragma unroll
        for (int i = 0; i < 4; ++i) { acc[i][0] *= rr; acc[i][1] *= rr; }
        WAIT_MFMA_PHASE();
#pragma unroll
        for (int i = 0; i < 4; ++i) { MFMA(i, 0, a[i], b01[0]); MFMA(i, 1, a[i], b01[1]); }
        END_MFMA_PHASE();

        // ---------- phase 1: i=0..3 x j=2..3 (+ prefetch B of kb+1)
        if (pf) STAGE_B(pn, nk0);
        LDB(b23[0], 2) LDB(b23[1], 3)
#pragma unroll
        for (int i = 0; i < 4; ++i) { acc[i][2] *= rr; acc[i][3] *= rr; }
        WAIT_MFMA_PHASE();
#pragma unroll
        for (int i = 0; i < 4; ++i) { MFMA(i, 2, a[i], b23[0]); MFMA(i, 3, a[i], b23[1]); }
        END_MFMA_PHASE();

        // ---------- phase 2: i=4..7 x j=2..3
        LDA(a[0], 4) LDA(a[1], 5) LDA(a[2], 6) LDA(a[3], 7)
#pragma unroll
        for (int i = 0; i < 4; ++i) { acc[4 + i][2] *= rr; acc[4 + i][3] *= rr; }
        WAIT_MFMA_PHASE();
#pragma unroll
        for (int i = 0; i < 4; ++i) { MFMA(4 + i, 2, a[i], b23[0]); MFMA(4 + i, 3, a[i], b23[1]); }
        END_MFMA_PHASE();

        // ---------- phase 3: i=4..7 x j=0..1 (b01 reloaded: cheaper than keeping live)
        LDB(b01[0], 0) LDB(b01[1], 1)
#pragma unroll
        for (int i = 0; i < 4; ++i) { acc[4 + i][0] *= rr; acc[4 + i][1] *= rr; }
        WAIT_MFMA_PHASE();
#pragma unroll
        for (int i = 0; i < 4; ++i) { MFMA(4 + i, 0, a[i], b01[0]); MFMA(4 + i, 1, a[i], b01[1]); }
        __builtin_amdgcn_s_setprio(0);
        // iteration end: __syncthreads drains vmcnt(0) (prefetch issued ~3
        // phases ago -> mostly landed) and is the one correctness barrier.
        __syncthreads();
    }

    // epilogue: D col=lane&15, row=(lane>>4)*4+reg; final scale = s_last * xs[token]
#pragma unroll
    for (int i = 0; i < 8; ++i) {
#pragma unroll
        for (int r = 0; r < 4; ++r) {
            const int m_g = bm * BM + wm + i * 16 + (lane >> 4) * 4 + r;
            const float f = xscale[m_g] * s_prev;
            float* crow = C + (size_t)m_g * O_OUT + bn * BN + wn;
#pragma unroll
            for (int j = 0; j < 4; ++j)
                crow[j * 16 + (lane & 15)] = acc[i][j][r] * f;
        }
    }
#undef STAGE_A
#undef STAGE_B
#undef LDA
#undef LDB
#undef MFMA
#undef WAIT_MFMA_PHASE
#undef END_MFMA_PHASE
}

// ---------- launch ----------
extern "C" void kernel_launch(void* const* d_in, const int* in_sizes, int n_in,
                              void* d_out, int out_size, void* d_ws, size_t ws_size,
                              hipStream_t stream) {
    const float* x    = (const float*)d_in[0];
    const float* w    = (const float*)d_in[1];
    const float* sinv = (const float*)d_in[2];
    float* out = (float*)d_out;

    char* ws = (char*)d_ws;
    uint32* xq = (uint32*)ws;                                   // 32 MB (fp8 bytes)
    uint32* wq = (uint32*)(ws + (size_t)T_TOK * K_IN);          // 24 MB
    float* xscale = (float*)(ws + (size_t)T_TOK * K_IN
                                + (size_t)O_OUT * K_IN);        // 32 KB

    quant_x<<<T_TOK, 256, 0, stream>>>(x, xq, xscale);
    quant_w<<<(O_OUT * K_IN) / (4 * 256), 256, 0, stream>>>(w, wq);
    dim3 grid(O_OUT / 256, T_TOK / 256);   // (24, 32)
    gemm_fp8<<<grid, 512, 131072 /*dynamic LDS: 2x(32K A + 32K B)*/, stream>>>(
        (const unsigned char*)xq, (const unsigned char*)wq, sinv, xscale, out);
}